// Round 7
// baseline (280.086 us; speedup 1.0000x reference)
//
#include <hip/hip_runtime.h>
#include <hip/hip_bf16.h>
#include <cstdint>
#include <cstddef>

// Problem constants
#define BB 4
#define SS 2048
#define DD 1024
#define HH 16
#define HDD 64

typedef __bf16 bf16_t;
typedef __bf16 bf16x8 __attribute__((ext_vector_type(8)));
typedef float f32x4 __attribute__((ext_vector_type(4)));
typedef unsigned u32x2 __attribute__((ext_vector_type(2)));

__device__ __forceinline__ unsigned short f2bf(float f) {
    unsigned u = __float_as_uint(f);
    unsigned r = (u + 0x7FFFu + ((u >> 16) & 1u)) >> 16;
    return (unsigned short)r;
}
__device__ __forceinline__ bf16_t f2bf16(float f) {
    return __builtin_bit_cast(bf16_t, f2bf(f));
}
__device__ __forceinline__ bf16x8 cvt8(float4 a, float4 b) {
    bf16x8 r;
    r[0] = f2bf16(a.x); r[1] = f2bf16(a.y);
    r[2] = f2bf16(a.z); r[3] = f2bf16(a.w);
    r[4] = f2bf16(b.x); r[5] = f2bf16(b.y);
    r[6] = f2bf16(b.z); r[7] = f2bf16(b.w);
    return r;
}
// packed f32x2 -> bf16x2 (RNE), lo16 = bf16(lo), hi16 = bf16(hi)
__device__ __forceinline__ unsigned cvtpk_bf16(float lo, float hi) {
    unsigned r;
    asm("v_cvt_pk_bf16_f32 %0, %1, %2" : "=v"(r) : "v"(lo), "v"(hi));
    return r;
}
// raw HW exp2: skips libm's denorm-guard sequence. 2^(-1e30) -> 0 in HW.
__device__ __forceinline__ float exp2_raw(float x) {
    float r;
    asm("v_exp_f32 %0, %1" : "=v"(r) : "v"(x));
    return r;
}

// async global->LDS, 16B per lane; LDS dest = wave-uniform base + lane*16
#define GLL16(gp, lp)                                                          \
    __builtin_amdgcn_global_load_lds(                                          \
        (const __attribute__((address_space(1))) void*)(gp),                   \
        (__attribute__((address_space(3))) void*)(lp), 16, 0, 0)

// ---------------------------------------------------------------------------
// fp32 -> bf16 converters (memory-bound, one-shot)
// ---------------------------------------------------------------------------
__global__ __launch_bounds__(256) void cvt1(const float* __restrict__ in,
                                            bf16_t* __restrict__ out) {
    size_t i = (size_t)blockIdx.x * 256 + threadIdx.x;
    const float4* p = (const float4*)in + i * 2;
    *(bf16x8*)(out + i * 8) = cvt8(p[0], p[1]);
}
__global__ __launch_bounds__(256) void cvt4(
    const float* __restrict__ w0, const float* __restrict__ w1,
    const float* __restrict__ w2, const float* __restrict__ w3,
    bf16_t* __restrict__ o0, bf16_t* __restrict__ o1,
    bf16_t* __restrict__ o2, bf16_t* __restrict__ o3) {
    const float* in = blockIdx.y == 0 ? w0 : blockIdx.y == 1 ? w1
                    : blockIdx.y == 2 ? w2 : w3;
    bf16_t* out = blockIdx.y == 0 ? o0 : blockIdx.y == 1 ? o1
                : blockIdx.y == 2 ? o2 : o3;
    size_t i = (size_t)blockIdx.x * 256 + threadIdx.x;
    const float4* p = (const float4*)in + i * 2;
    *(bf16x8*)(out + i * 8) = cvt8(p[0], p[1]);
}

// ---------------------------------------------------------------------------
// Fused QKV projection: C(8192x3072) = xb(8192x1024) @ [wq;wk;wv]^T.
// wb0..wb2 are contiguous -> single W with 3072 rows. Per-block sub-mode
// decoded block-uniformly from n0>>10: 0=Q (RoPE, qscale), 1=K (RoPE, 1.0),
// 2=V (transposed write). m97 staging pattern, grid (24,64) = 1536 blocks.
// ---------------------------------------------------------------------------
__global__ __launch_bounds__(256, 2) void gemm_qkv(
    const bf16_t* __restrict__ A, const bf16_t* __restrict__ Wall,
    bf16_t* __restrict__ Qb, bf16_t* __restrict__ Kb,
    bf16_t* __restrict__ Vt,
    const float* __restrict__ fcos, const float* __restrict__ fsin,
    float qscale)
{
    constexpr int K = 1024;
    __shared__ alignas(16) bf16_t lA[128 * 64];
    __shared__ alignas(16) bf16_t lB[128 * 64];

    const int tid  = threadIdx.x;
    const int w    = tid >> 6;
    const int lane = tid & 63;
    const int quad = lane >> 4;
    const int l16  = lane & 15;
    const int wm   = w >> 1;
    const int wn   = w & 1;
    const int m0   = blockIdx.y * 128;
    const int n0   = blockIdx.x * 128;   // 0..2944 over the stacked weights
    const int sub  = n0 >> 10;           // 0=Q, 1=K, 2=V (block-uniform)

    f32x4 acc[4][4];
#pragma unroll
    for (int i = 0; i < 4; i++)
#pragma unroll
        for (int j = 0; j < 4; j++) acc[i][j] = (f32x4){0.f, 0.f, 0.f, 0.f};

    const int srow8 = lane >> 3;
    const int slot  = lane & 7;

    for (int k0 = 0; k0 < K; k0 += 64) {
#pragma unroll
        for (int i = 0; i < 4; ++i) {
            int row = w * 32 + i * 8;
            GLL16(A + (size_t)(m0 + row + srow8) * K + k0 + slot * 8,
                  &lA[row * 64]);
            GLL16(Wall + (size_t)(n0 + row + srow8) * K + k0 + slot * 8,
                  &lB[row * 64]);
        }
        __syncthreads();
#pragma unroll
        for (int kk = 0; kk < 2; ++kk) {
            bf16x8 af[4], bfr[4];
#pragma unroll
            for (int mt = 0; mt < 4; ++mt)
                af[mt] = *(const bf16x8*)
                    &lA[(wm * 64 + mt * 16 + l16) * 64 + (kk * 4 + quad) * 8];
#pragma unroll
            for (int nt = 0; nt < 4; ++nt)
                bfr[nt] = *(const bf16x8*)
                    &lB[(wn * 64 + nt * 16 + l16) * 64 + (kk * 4 + quad) * 8];
#pragma unroll
            for (int mt = 0; mt < 4; ++mt)
#pragma unroll
                for (int nt = 0; nt < 4; ++nt)
                    acc[mt][nt] = __builtin_amdgcn_mfma_f32_16x16x32_bf16(
                        af[mt], bfr[nt], acc[mt][nt], 0, 0, 0);
        }
        __syncthreads();
    }

    if (sub < 2) {
        // RoPE + scale, write bf16 (B,H,S,HD)
        unsigned short* Cu = (unsigned short*)(sub == 0 ? Qb : Kb);
        const float scale = sub == 0 ? qscale : 1.0f;
#pragma unroll
        for (int mt = 0; mt < 4; ++mt) {
#pragma unroll
            for (int nt = 0; nt < 4; ++nt) {
                int col  = (n0 & 1023) + wn * 64 + nt * 16 + l16;
                int h    = col >> 6;
                int d    = col & 63;
                int pidx = d >> 1;
                bool even = (col & 1) == 0;
#pragma unroll
                for (int r = 0; r < 4; ++r) {
                    int m = m0 + wm * 64 + mt * 16 + quad * 4 + r;
                    int b = m >> 11;   // / S
                    int s = m & 2047;  // % S
                    float v  = acc[mt][nt][r];
                    float p  = __shfl_xor(v, 1);
                    float c  = fcos[s * 32 + pidx];
                    float sn = fsin[s * 32 + pidx];
                    float o  = even ? (v * c - p * sn) : (p * sn + v * c);
                    Cu[(size_t)((b * HH + h) * SS + s) * HDD + d] =
                        f2bf(o * scale);
                }
            }
        }
    } else {
        // V: write bf16 transposed (B,H,HD,S)
        unsigned short* Cu = (unsigned short*)Vt;
#pragma unroll
        for (int mt = 0; mt < 4; ++mt) {
#pragma unroll
            for (int nt = 0; nt < 4; ++nt) {
                int col = (n0 & 1023) + wn * 64 + nt * 16 + l16;
                int h = col >> 6, d = col & 63;
#pragma unroll
                for (int r = 0; r < 4; ++r) {
                    int m = m0 + wm * 64 + mt * 16 + quad * 4 + r;
                    int b = m >> 11, s = m & 2047;
                    Cu[(size_t)((b * HH + h) * HDD + d) * SS + s] =
                        f2bf(acc[mt][nt][r]);
                }
            }
        }
    }
}

// ---------------------------------------------------------------------------
// Final projection: C(MxN) = A(MxK) @ W^T, fp32 row-major output.
// (R5's known-good single-buffer version; R6's dbuf was neutral-to-negative.)
// ---------------------------------------------------------------------------
__global__ __launch_bounds__(256, 2) void gemm_out(
    const bf16_t* __restrict__ A, const bf16_t* __restrict__ W,
    float* __restrict__ Cf)
{
    constexpr int K = 1024, N = 1024;
    __shared__ alignas(16) bf16_t lA[128 * 64];
    __shared__ alignas(16) bf16_t lB[128 * 64];

    const int tid  = threadIdx.x;
    const int w    = tid >> 6;
    const int lane = tid & 63;
    const int quad = lane >> 4;
    const int l16  = lane & 15;
    const int wm   = w >> 1;
    const int wn   = w & 1;
    const int m0   = blockIdx.y * 128;
    const int n0   = blockIdx.x * 128;

    f32x4 acc[4][4];
#pragma unroll
    for (int i = 0; i < 4; i++)
#pragma unroll
        for (int j = 0; j < 4; j++) acc[i][j] = (f32x4){0.f, 0.f, 0.f, 0.f};

    const int srow8 = lane >> 3;
    const int slot  = lane & 7;

    for (int k0 = 0; k0 < K; k0 += 64) {
#pragma unroll
        for (int i = 0; i < 4; ++i) {
            int row = w * 32 + i * 8;
            GLL16(A + (size_t)(m0 + row + srow8) * K + k0 + slot * 8,
                  &lA[row * 64]);
            GLL16(W + (size_t)(n0 + row + srow8) * K + k0 + slot * 8,
                  &lB[row * 64]);
        }
        __syncthreads();
#pragma unroll
        for (int kk = 0; kk < 2; ++kk) {
            bf16x8 af[4], bfr[4];
#pragma unroll
            for (int mt = 0; mt < 4; ++mt)
                af[mt] = *(const bf16x8*)
                    &lA[(wm * 64 + mt * 16 + l16) * 64 + (kk * 4 + quad) * 8];
#pragma unroll
            for (int nt = 0; nt < 4; ++nt)
                bfr[nt] = *(const bf16x8*)
                    &lB[(wn * 64 + nt * 16 + l16) * 64 + (kk * 4 + quad) * 8];
#pragma unroll
            for (int mt = 0; mt < 4; ++mt)
#pragma unroll
                for (int nt = 0; nt < 4; ++nt)
                    acc[mt][nt] = __builtin_amdgcn_mfma_f32_16x16x32_bf16(
                        af[mt], bfr[nt], acc[mt][nt], 0, 0, 0);
        }
        __syncthreads();
    }

#pragma unroll
    for (int mt = 0; mt < 4; ++mt) {
        int mrow = m0 + wm * 64 + mt * 16 + quad * 4;
#pragma unroll
        for (int nt = 0; nt < 4; ++nt) {
            int col = n0 + wn * 64 + nt * 16 + l16;
#pragma unroll
            for (int r = 0; r < 4; ++r)
                Cf[(size_t)(mrow + r) * N + col] = acc[mt][nt][r];
        }
    }
}

// ---------------------------------------------------------------------------
// Flash attention v10 — KVBLK=128: fewer, fatter iterations.
// R3/R5/R6 invariant: ~86-89us, MfmaUtil ~15.7 (=384 TF, FLOP-consistent),
// VALU ~33, HBM 6%, dbuf neutral -> not latency-bound on staging; the cost
// is the per-iteration sync quantum (34 barrier-paired iterations, each
// ~3x longer than its pipe work: barrier skew + drain + short scheduling
// windows). Fix: stage a 128-row K tile (128x64) + V tile (64x128) per
// iteration (32KB single-buffered, same LDS as R6) and run the compute
// body TWICE (two 64-wide k-passes) between ONE barrier pair. Iterations
// and barriers halve; the compiler gets 2x the straight-line region.
// Swizzle: 16B-chunk XOR involution per row, p-bit (chunk bit 3 on V)
// untouched. Causal logic parameterized per pass. p-loop not force-unrolled
// (sequential passes keep VGPR at R5 level - rule: avoid spill cliff).
// Geometry: 1024 blocks, heavy/light T interleave, XCD-affinity,
// raw v_exp_f32, exec-skipped diag mask, in-register softmax/P-transpose.
// ---------------------------------------------------------------------------
__global__ __launch_bounds__(256, 2) void attn(
    const bf16_t* __restrict__ Q, const bf16_t* __restrict__ Kt,
    const bf16_t* __restrict__ Vt, bf16_t* __restrict__ O)
{
    __shared__ alignas(16) bf16_t lK[128 * 64];  // 16 KiB, k-row x hd
    __shared__ alignas(16) bf16_t lV[64 * 128];  // 16 KiB, hd x k-col

    const int tid  = threadIdx.x;
    const int w    = tid >> 6;
    const int lane = tid & 63;
    const int quad = lane >> 4;
    const int l16  = lane & 15;

    // XCD-affinity decode: all 16 blocks of a given bh land on XCD bh&7.
    // j interleaves heavy/light super-tiles: T = {15,0,14,1,...}.
    const int blk  = blockIdx.x;          // 0..1023
    const int xcd  = blk & 7;
    const int rest = blk >> 3;            // 0..127
    const int j    = rest & 15;           // 0..15
    const int bh   = ((rest >> 4) << 3) | xcd;
    const int T    = (j & 1) ? (j >> 1) : (15 - (j >> 1));

    const int b = bh >> 4, h = bh & 15;
    unsigned short* Ou = (unsigned short*)O;
    const bf16_t* Qb = Q  + (size_t)bh * SS * HDD;
    const bf16_t* Kb = Kt + (size_t)bh * SS * HDD;
    const bf16_t* Vb = Vt + (size_t)bh * HDD * SS;

    const int q0 = T * 128 + w * 32;      // this wave's 32 q-rows
    const int nt128 = T + 1;              // 128-wide k-tile count

    // staging: K = 128 rows x 128B (32 rows/wave, 8 rows/GLL16);
    //          V = 64 rows x 256B (16 rows/wave, 4 rows/GLL16).
    // Source 16B-chunk XOR-swizzled by (row&7) so the swizzled ds_read on
    // the consume side sees the identity mapping (involution, both sides).
    const int krow_l = lane >> 3;          // 0..7 within an 8-row K group
    const int kchk   = lane & 7;           // 16B chunk within 128B K row
    const int vrow_l = lane >> 4;          // 0..3 within a 4-row V group
    const int vchk   = lane & 15;          // 16B chunk within 256B V row

    auto stage = [&](int kb2) {
#pragma unroll
        for (int i = 0; i < 4; ++i) {
            int row = w * 32 + i * 8 + krow_l;
            GLL16(Kb + (size_t)(kb2 + row) * HDD + ((kchk ^ (row & 7)) * 8),
                  &lK[(w * 32 + i * 8) * 64]);
        }
#pragma unroll
        for (int i = 0; i < 4; ++i) {
            int row = w * 16 + i * 4 + vrow_l;
            GLL16(Vb + (size_t)row * SS + kb2 + ((vchk ^ (row & 7)) * 8),
                  &lV[(w * 16 + i * 4) * 128]);
        }
    };

    // Q fragments (B-operand of swapped QK^T), direct global
    bf16x8 qf[2][2];
#pragma unroll
    for (int qs = 0; qs < 2; ++qs) {
        const bf16_t* qp =
            Qb + (size_t)(q0 + qs * 16 + l16) * HDD + quad * 8;
        qf[qs][0] = *(const bf16x8*)(qp);
        qf[qs][1] = *(const bf16x8*)(qp + 32);
    }

    f32x4 o[2][4];
    float ps[2];
#pragma unroll
    for (int qs = 0; qs < 2; ++qs) {
        ps[qs] = 0.f;
#pragma unroll
        for (int i = 0; i < 4; ++i) o[qs][i] = (f32x4){0.f, 0.f, 0.f, 0.f};
    }

    for (int t = 0; t < nt128; ++t) {
        const int kb2 = t * 128;
        stage(kb2);
        __syncthreads();   // vmcnt(0) drain + all waves' tiles ready

        for (int p = 0; p < 2; ++p) {      // two 64-wide k-passes per tile
            const int kbp = kb2 + p * 64;
            if (kbp < q0 + 32) {           // wave-uniform: skip fully-masked
                const bool diag = (kbp + 63 > q0);

                // K fragments from LDS (swizzled read), rows p*64..p*64+63
                bf16x8 kf[4][2];
#pragma unroll
                for (int nt = 0; nt < 4; ++nt) {
                    const int row = p * 64 + nt * 16 + l16;
#pragma unroll
                    for (int hf = 0; hf < 2; ++hf)
                        kf[nt][hf] = *(const bf16x8*)
                            &lK[row * 64 + (((hf * 4 + quad) ^ (row & 7)) * 8)];
                }
                // V fragments from LDS (swizzled read), cols p*64..p*64+63
                bf16x8 vf[2][4];
#pragma unroll
                for (int kk = 0; kk < 2; ++kk)
#pragma unroll
                    for (int nt = 0; nt < 4; ++nt) {
                        const int row = nt * 16 + l16;
                        vf[kk][nt] = *(const bf16x8*)
                            &lV[row * 128 +
                                ((p * 8 + ((kk * 4 + quad) ^ (row & 7))) * 8)];
                    }

                // scores (transposed) + exp + in-lane bf16 pack
                unsigned pk[4][2][2];
#pragma unroll
                for (int nt = 0; nt < 4; ++nt) {
                    const int krow = kbp + nt * 16 + quad * 4;
#pragma unroll
                    for (int qs = 0; qs < 2; ++qs) {
                        f32x4 s = (f32x4){0.f, 0.f, 0.f, 0.f};
                        s = __builtin_amdgcn_mfma_f32_16x16x32_bf16(
                            kf[nt][0], qf[qs][0], s, 0, 0, 0);
                        s = __builtin_amdgcn_mfma_f32_16x16x32_bf16(
                            kf[nt][1], qf[qs][1], s, 0, 0, 0);
                        if (diag) {        // exec-skipped off the diagonal
                            const int qcol = q0 + qs * 16 + l16;
#pragma unroll
                            for (int r = 0; r < 4; ++r)
                                if (krow + r > qcol) s[r] = -1e30f;
                        }
                        float ev[4];
#pragma unroll
                        for (int r = 0; r < 4; ++r) {
                            float e = exp2_raw(s[r]);   // scaled via Q-fold
                            ps[qs] += e;
                            ev[r] = e;
                        }
                        pk[nt][qs][0] = cvtpk_bf16(ev[0], ev[1]);
                        pk[nt][qs][1] = cvtpk_bf16(ev[2], ev[3]);
                    }
                }

                // register-only P-transpose + PV accumulation
#pragma unroll
                for (int kk = 0; kk < 2; ++kk) {
#pragma unroll
                    for (int qs = 0; qs < 2; ++qs) {
                        u32x2 sA = __builtin_amdgcn_permlane32_swap(
                            pk[2 * kk][qs][0], pk[2 * kk + 1][qs][0],
                            false, false);
                        u32x2 sB = __builtin_amdgcn_permlane32_swap(
                            pk[2 * kk][qs][1], pk[2 * kk + 1][qs][1],
                            false, false);
                        u32x2 tA = __builtin_amdgcn_permlane16_swap(
                            sA.x, sA.y, false, false);
                        u32x2 tB = __builtin_amdgcn_permlane16_swap(
                            sB.x, sB.y, false, false);
                        union { unsigned d[4]; bf16x8 v; } pf;
                        pf.d[0] = tA.x;  // k-pair (0,1) of quad*8
                        pf.d[1] = tB.x;  // k-pair (2,3)
                        pf.d[2] = tA.y;  // k-pair (4,5)
                        pf.d[3] = tB.y;  // k-pair (6,7)
#pragma unroll
                        for (int nt = 0; nt < 4; ++nt)
                            o[qs][nt] = __builtin_amdgcn_mfma_f32_16x16x32_bf16(
                                pf.v, vf[kk][nt], o[qs][nt], 0, 0, 0);
                    }
                }
            }
        }
        __syncthreads();   // compute done before next iter's staging
    }

    // epilogue: quad-reduce row sums, redistribute, O/l, write bf16
#pragma unroll
    for (int qs = 0; qs < 2; ++qs) {
        float tsum = ps[qs];
        tsum += __shfl_xor(tsum, 16);
        tsum += __shfl_xor(tsum, 32);
        // every lane now holds rowsum(q = q0+qs*16+l16)
        float inv[4];
#pragma unroll
        for (int r = 0; r < 4; ++r)
            inv[r] = 1.0f / __shfl(tsum, quad * 4 + r);
#pragma unroll
        for (int nt = 0; nt < 4; ++nt) {
            int d = nt * 16 + l16;
#pragma unroll
            for (int r = 0; r < 4; ++r) {
                int s = q0 + qs * 16 + quad * 4 + r;
                Ou[(size_t)(b * SS + s) * DD + h * HDD + d] =
                    f2bf(o[qs][nt][r] * inv[r]);
            }
        }
    }
}

// ---------------------------------------------------------------------------
// Buffer plan.  TSZ = B*S*D bf16 = 16 MiB; WSZ = D*D bf16 = 2 MiB.
//   d_out (32 MiB fp32): [0,TSZ) = xb, [TSZ,2*TSZ) = Vt — both dead before
//     the final GEMM overwrites d_out (it reads only Ob, wb3).
//   ws: Qb | Kb | Ob | wb0..3 = 56 MiB.  wb0..wb2 contiguous = stacked QKV W.
// ---------------------------------------------------------------------------
extern "C" void kernel_launch(void* const* d_in, const int* in_sizes, int n_in,
                              void* d_out, int out_size, void* d_ws,
                              size_t ws_size, hipStream_t stream)
{
    const float* x    = (const float*)d_in[0];
    const float* fcos = (const float*)d_in[1];
    const float* fsin = (const float*)d_in[2];
    const float* wq   = (const float*)d_in[3];
    const float* wk   = (const float*)d_in[4];
    const float* wv   = (const float*)d_in[5];
    const float* wo   = (const float*)d_in[6];

    char* ws = (char*)d_ws;
    const size_t TSZ = (size_t)BB * SS * DD * sizeof(bf16_t);  // 16 MiB
    const size_t WSZ = (size_t)DD * DD * sizeof(bf16_t);       // 2 MiB
    bf16_t* Qb  = (bf16_t*)(ws);
    bf16_t* Kb  = (bf16_t*)(ws + TSZ);
    bf16_t* Ob  = (bf16_t*)(ws + 2 * TSZ);
    bf16_t* wb0 = (bf16_t*)(ws + 3 * TSZ);
    bf16_t* wb1 = (bf16_t*)(ws + 3 * TSZ + WSZ);
    bf16_t* wb2 = (bf16_t*)(ws + 3 * TSZ + 2 * WSZ);
    bf16_t* wb3 = (bf16_t*)(ws + 3 * TSZ + 3 * WSZ);
    bf16_t* xb  = (bf16_t*)d_out;
    bf16_t* Vt  = (bf16_t*)((char*)d_out + TSZ);

    dim3 bb(256);
    cvt1<<<dim3(4096), bb, 0, stream>>>(x, xb);
    cvt4<<<dim3(512, 4), bb, 0, stream>>>(wq, wk, wv, wo, wb0, wb1, wb2, wb3);

    const float sscale = 0.125f * 1.44269504088896f;  // 1/sqrt(64)*log2(e)
    gemm_qkv<<<dim3(24, 64), bb, 0, stream>>>(xb, wb0, Qb, Kb, Vt,
                                              fcos, fsin, sscale);
    attn<<<dim3(1024), bb, 0, stream>>>(Qb, Kb, Vt, Ob);
    gemm_out<<<dim3(8, 64), bb, 0, stream>>>(Ob, wb3, (float*)d_out);
}

// Round 8
// 278.049 us; speedup vs baseline: 1.0073x; 1.0073x over previous
//
#include <hip/hip_runtime.h>
#include <hip/hip_bf16.h>
#include <cstdint>
#include <cstddef>

// Problem constants
#define BB 4
#define SS 2048
#define DD 1024
#define HH 16
#define HDD 64

typedef __bf16 bf16_t;
typedef __bf16 bf16x8 __attribute__((ext_vector_type(8)));
typedef float f32x4 __attribute__((ext_vector_type(4)));
typedef unsigned u32x2 __attribute__((ext_vector_type(2)));

__device__ __forceinline__ unsigned short f2bf(float f) {
    unsigned u = __float_as_uint(f);
    unsigned r = (u + 0x7FFFu + ((u >> 16) & 1u)) >> 16;
    return (unsigned short)r;
}
__device__ __forceinline__ bf16_t f2bf16(float f) {
    return __builtin_bit_cast(bf16_t, f2bf(f));
}
__device__ __forceinline__ bf16x8 cvt8(float4 a, float4 b) {
    bf16x8 r;
    r[0] = f2bf16(a.x); r[1] = f2bf16(a.y);
    r[2] = f2bf16(a.z); r[3] = f2bf16(a.w);
    r[4] = f2bf16(b.x); r[5] = f2bf16(b.y);
    r[6] = f2bf16(b.z); r[7] = f2bf16(b.w);
    return r;
}
// packed f32x2 -> bf16x2 (RNE), lo16 = bf16(lo), hi16 = bf16(hi)
__device__ __forceinline__ unsigned cvtpk_bf16(float lo, float hi) {
    unsigned r;
    asm("v_cvt_pk_bf16_f32 %0, %1, %2" : "=v"(r) : "v"(lo), "v"(hi));
    return r;
}
// raw HW exp2: skips libm's denorm-guard sequence. 2^(-1e30) -> 0 in HW.
__device__ __forceinline__ float exp2_raw(float x) {
    float r;
    asm("v_exp_f32 %0, %1" : "=v"(r) : "v"(x));
    return r;
}

// async global->LDS, 16B per lane; LDS dest = wave-uniform base + lane*16
#define GLL16(gp, lp)                                                          \
    __builtin_amdgcn_global_load_lds(                                          \
        (const __attribute__((address_space(1))) void*)(gp),                   \
        (__attribute__((address_space(3))) void*)(lp), 16, 0, 0)

// ---------------------------------------------------------------------------
// fp32 -> bf16 converters (memory-bound, one-shot)
// ---------------------------------------------------------------------------
__global__ __launch_bounds__(256) void cvt1(const float* __restrict__ in,
                                            bf16_t* __restrict__ out) {
    size_t i = (size_t)blockIdx.x * 256 + threadIdx.x;
    const float4* p = (const float4*)in + i * 2;
    *(bf16x8*)(out + i * 8) = cvt8(p[0], p[1]);
}
__global__ __launch_bounds__(256) void cvt4(
    const float* __restrict__ w0, const float* __restrict__ w1,
    const float* __restrict__ w2, const float* __restrict__ w3,
    bf16_t* __restrict__ o0, bf16_t* __restrict__ o1,
    bf16_t* __restrict__ o2, bf16_t* __restrict__ o3) {
    const float* in = blockIdx.y == 0 ? w0 : blockIdx.y == 1 ? w1
                    : blockIdx.y == 2 ? w2 : w3;
    bf16_t* out = blockIdx.y == 0 ? o0 : blockIdx.y == 1 ? o1
                : blockIdx.y == 2 ? o2 : o3;
    size_t i = (size_t)blockIdx.x * 256 + threadIdx.x;
    const float4* p = (const float4*)in + i * 2;
    *(bf16x8*)(out + i * 8) = cvt8(p[0], p[1]);
}

// ---------------------------------------------------------------------------
// Fused QKV projection: C(8192x3072) = xb(8192x1024) @ [wq;wk;wv]^T.
// wb0..wb2 are contiguous -> single W with 3072 rows. Per-block sub-mode
// decoded block-uniformly from n0>>10: 0=Q (RoPE, qscale), 1=K (RoPE, 1.0),
// 2=V (transposed write). m97 staging pattern, grid (24,64) = 1536 blocks.
// ---------------------------------------------------------------------------
__global__ __launch_bounds__(256, 2) void gemm_qkv(
    const bf16_t* __restrict__ A, const bf16_t* __restrict__ Wall,
    bf16_t* __restrict__ Qb, bf16_t* __restrict__ Kb,
    bf16_t* __restrict__ Vt,
    const float* __restrict__ fcos, const float* __restrict__ fsin,
    float qscale)
{
    constexpr int K = 1024;
    __shared__ alignas(16) bf16_t lA[128 * 64];
    __shared__ alignas(16) bf16_t lB[128 * 64];

    const int tid  = threadIdx.x;
    const int w    = tid >> 6;
    const int lane = tid & 63;
    const int quad = lane >> 4;
    const int l16  = lane & 15;
    const int wm   = w >> 1;
    const int wn   = w & 1;
    const int m0   = blockIdx.y * 128;
    const int n0   = blockIdx.x * 128;   // 0..2944 over the stacked weights
    const int sub  = n0 >> 10;           // 0=Q, 1=K, 2=V (block-uniform)

    f32x4 acc[4][4];
#pragma unroll
    for (int i = 0; i < 4; i++)
#pragma unroll
        for (int j = 0; j < 4; j++) acc[i][j] = (f32x4){0.f, 0.f, 0.f, 0.f};

    const int srow8 = lane >> 3;
    const int slot  = lane & 7;

    for (int k0 = 0; k0 < K; k0 += 64) {
#pragma unroll
        for (int i = 0; i < 4; ++i) {
            int row = w * 32 + i * 8;
            GLL16(A + (size_t)(m0 + row + srow8) * K + k0 + slot * 8,
                  &lA[row * 64]);
            GLL16(Wall + (size_t)(n0 + row + srow8) * K + k0 + slot * 8,
                  &lB[row * 64]);
        }
        __syncthreads();
#pragma unroll
        for (int kk = 0; kk < 2; ++kk) {
            bf16x8 af[4], bfr[4];
#pragma unroll
            for (int mt = 0; mt < 4; ++mt)
                af[mt] = *(const bf16x8*)
                    &lA[(wm * 64 + mt * 16 + l16) * 64 + (kk * 4 + quad) * 8];
#pragma unroll
            for (int nt = 0; nt < 4; ++nt)
                bfr[nt] = *(const bf16x8*)
                    &lB[(wn * 64 + nt * 16 + l16) * 64 + (kk * 4 + quad) * 8];
#pragma unroll
            for (int mt = 0; mt < 4; ++mt)
#pragma unroll
                for (int nt = 0; nt < 4; ++nt)
                    acc[mt][nt] = __builtin_amdgcn_mfma_f32_16x16x32_bf16(
                        af[mt], bfr[nt], acc[mt][nt], 0, 0, 0);
        }
        __syncthreads();
    }

    if (sub < 2) {
        // RoPE + scale, write bf16 (B,H,S,HD)
        unsigned short* Cu = (unsigned short*)(sub == 0 ? Qb : Kb);
        const float scale = sub == 0 ? qscale : 1.0f;
#pragma unroll
        for (int mt = 0; mt < 4; ++mt) {
#pragma unroll
            for (int nt = 0; nt < 4; ++nt) {
                int col  = (n0 & 1023) + wn * 64 + nt * 16 + l16;
                int h    = col >> 6;
                int d    = col & 63;
                int pidx = d >> 1;
                bool even = (col & 1) == 0;
#pragma unroll
                for (int r = 0; r < 4; ++r) {
                    int m = m0 + wm * 64 + mt * 16 + quad * 4 + r;
                    int b = m >> 11;   // / S
                    int s = m & 2047;  // % S
                    float v  = acc[mt][nt][r];
                    float p  = __shfl_xor(v, 1);
                    float c  = fcos[s * 32 + pidx];
                    float sn = fsin[s * 32 + pidx];
                    float o  = even ? (v * c - p * sn) : (p * sn + v * c);
                    Cu[(size_t)((b * HH + h) * SS + s) * HDD + d] =
                        f2bf(o * scale);
                }
            }
        }
    } else {
        // V: write bf16 transposed (B,H,HD,S)
        unsigned short* Cu = (unsigned short*)Vt;
#pragma unroll
        for (int mt = 0; mt < 4; ++mt) {
#pragma unroll
            for (int nt = 0; nt < 4; ++nt) {
                int col = (n0 & 1023) + wn * 64 + nt * 16 + l16;
                int h = col >> 6, d = col & 63;
#pragma unroll
                for (int r = 0; r < 4; ++r) {
                    int m = m0 + wm * 64 + mt * 16 + quad * 4 + r;
                    int b = m >> 11, s = m & 2047;
                    Cu[(size_t)((b * HH + h) * HDD + d) * SS + s] =
                        f2bf(acc[mt][nt][r]);
                }
            }
        }
    }
}

// ---------------------------------------------------------------------------
// Final projection: C(MxN) = A(MxK) @ W^T, fp32 row-major output.
// ---------------------------------------------------------------------------
__global__ __launch_bounds__(256, 2) void gemm_out(
    const bf16_t* __restrict__ A, const bf16_t* __restrict__ W,
    float* __restrict__ Cf)
{
    constexpr int K = 1024, N = 1024;
    __shared__ alignas(16) bf16_t lA[128 * 64];
    __shared__ alignas(16) bf16_t lB[128 * 64];

    const int tid  = threadIdx.x;
    const int w    = tid >> 6;
    const int lane = tid & 63;
    const int quad = lane >> 4;
    const int l16  = lane & 15;
    const int wm   = w >> 1;
    const int wn   = w & 1;
    const int m0   = blockIdx.y * 128;
    const int n0   = blockIdx.x * 128;

    f32x4 acc[4][4];
#pragma unroll
    for (int i = 0; i < 4; i++)
#pragma unroll
        for (int j = 0; j < 4; j++) acc[i][j] = (f32x4){0.f, 0.f, 0.f, 0.f};

    const int srow8 = lane >> 3;
    const int slot  = lane & 7;

    for (int k0 = 0; k0 < K; k0 += 64) {
#pragma unroll
        for (int i = 0; i < 4; ++i) {
            int row = w * 32 + i * 8;
            GLL16(A + (size_t)(m0 + row + srow8) * K + k0 + slot * 8,
                  &lA[row * 64]);
            GLL16(W + (size_t)(n0 + row + srow8) * K + k0 + slot * 8,
                  &lB[row * 64]);
        }
        __syncthreads();
#pragma unroll
        for (int kk = 0; kk < 2; ++kk) {
            bf16x8 af[4], bfr[4];
#pragma unroll
            for (int mt = 0; mt < 4; ++mt)
                af[mt] = *(const bf16x8*)
                    &lA[(wm * 64 + mt * 16 + l16) * 64 + (kk * 4 + quad) * 8];
#pragma unroll
            for (int nt = 0; nt < 4; ++nt)
                bfr[nt] = *(const bf16x8*)
                    &lB[(wn * 64 + nt * 16 + l16) * 64 + (kk * 4 + quad) * 8];
#pragma unroll
            for (int mt = 0; mt < 4; ++mt)
#pragma unroll
                for (int nt = 0; nt < 4; ++nt)
                    acc[mt][nt] = __builtin_amdgcn_mfma_f32_16x16x32_bf16(
                        af[mt], bfr[nt], acc[mt][nt], 0, 0, 0);
        }
        __syncthreads();
    }

#pragma unroll
    for (int mt = 0; mt < 4; ++mt) {
        int mrow = m0 + wm * 64 + mt * 16 + quad * 4;
#pragma unroll
        for (int nt = 0; nt < 4; ++nt) {
            int col = n0 + wn * 64 + nt * 16 + l16;
#pragma unroll
            for (int r = 0; r < 4; ++r)
                Cf[(size_t)(mrow + r) * N + col] = acc[mt][nt][r];
        }
    }
}

// ---------------------------------------------------------------------------
// Flash attention v11 — 64 q-rows/wave, uniform pairing, half the LDS reads.
// R3/R6/R7 invariant (~87us) localized the bound: (1) every wave reads the
// whole K/V tile (B-operand), so ds_read traffic = 1.11GB ~= LDS ceiling on
// active CUs; (2) work ~ T+1 per block -> long sparse tail (Occ 12-15%).
// Fix: block = 256 q-rows (4 waves x 64 rows, qs=0..3) -> same 32KB/tile
// feeds 2x the MFMA/exp per wave => LDS reads halve (0.59GB). Pair
// super-tiles (T',7-T') sequentially -> EVERY block runs exactly 18
// 128-wide k-tiles; grid = 256 = 1 block/CU, zero tail. V stored as two
// [64][64] sub-tiles (one per 64-pass) staged as 8-row x 8-chunk GLL16
// groups = exactly the proven conflict-free K layout (R7's [64][128] was a
// measured 2.16M-conflict mistake). Double-buffered staging (at 1 block/CU
// there is no co-resident block to hide the drain, so dbuf finally pays).
// ---------------------------------------------------------------------------
__global__ __launch_bounds__(256, 2) void attn(
    const bf16_t* __restrict__ Q, const bf16_t* __restrict__ Kt,
    const bf16_t* __restrict__ Vt, bf16_t* __restrict__ O)
{
    __shared__ alignas(16) bf16_t lK[2][128 * 64];    // 2 x 16 KiB
    __shared__ alignas(16) bf16_t lV[2][2][64 * 64];  // 2 x 2 x 8 KiB

    const int tid  = threadIdx.x;
    const int w    = tid >> 6;
    const int lane = tid & 63;
    const int quad = lane >> 4;
    const int l16  = lane & 15;

    // XCD-affinity decode: all 4 blocks of a given bh land on XCD bh&7.
    const int blk  = blockIdx.x;          // 0..255
    const int xcd  = blk & 7;
    const int rest = blk >> 3;            // 0..31
    const int g    = rest & 3;            // pair index 0..3
    const int bh   = ((rest >> 2) << 3) | xcd;

    const int b = bh >> 4, h = bh & 15;
    unsigned short* Ou = (unsigned short*)O;
    const bf16_t* Qb = Q  + (size_t)bh * SS * HDD;
    const bf16_t* Kb = Kt + (size_t)bh * SS * HDD;
    const bf16_t* Vb = Vt + (size_t)bh * HDD * SS;

    // staging lane geometry: 8-row x 8-chunk GLL16 groups, source chunk
    // XOR-swizzled by (row&7) (involution; read side applies the same XOR).
    const int row8 = lane >> 3;            // 0..7 row within a group
    const int chk  = lane & 7;             // 16B chunk within a 128B row

    for (int phase = 0; phase < 2; ++phase) {
        const int Tp  = phase ? 7 - g : g;    // 256-row super-tile index
        const int q0  = Tp * 256 + w * 64;    // this wave's 64 q-rows
        const int nkb = 2 * Tp + 2;           // 128-wide k-tile count

        // Q fragments (B-operand of swapped QK^T), direct global
        bf16x8 qf[4][2];
#pragma unroll
        for (int qs = 0; qs < 4; ++qs) {
            const bf16_t* qp =
                Qb + (size_t)(q0 + qs * 16 + l16) * HDD + quad * 8;
            qf[qs][0] = *(const bf16x8*)(qp);
            qf[qs][1] = *(const bf16x8*)(qp + 32);
        }

        f32x4 o[4][4];
        float ps[4];
#pragma unroll
        for (int qs = 0; qs < 4; ++qs) {
            ps[qs] = 0.f;
#pragma unroll
            for (int i = 0; i < 4; ++i) o[qs][i] = (f32x4){0.f, 0.f, 0.f, 0.f};
        }

        auto stage = [&](int kb2, int buf) {
            // K: wave stages rows [w*32, w*32+32), 4 GLL16 (8 rows each)
#pragma unroll
            for (int i = 0; i < 4; ++i) {
                int rbase = w * 32 + i * 8;
                int row   = rbase + row8;
                GLL16(Kb + (size_t)(kb2 + row) * HDD + ((chk ^ (row & 7)) * 8),
                      &lK[buf][rbase * 64]);
            }
            // V: wave stages d-rows [w*16, w*16+16), 2 groups x 2 sub-tiles
#pragma unroll
            for (int pp = 0; pp < 2; ++pp)
#pragma unroll
                for (int i = 0; i < 2; ++i) {
                    int rbase = w * 16 + i * 8;
                    int row   = rbase + row8;
                    GLL16(Vb + (size_t)row * SS + kb2 + pp * 64 +
                              ((chk ^ (row & 7)) * 8),
                          &lV[buf][pp][rbase * 64]);
                }
        };

        stage(0, 0);
        __syncthreads();   // buf0 ready

        for (int t = 0; t < nkb; ++t) {
            const int kb2 = t * 128;
            const int cur = t & 1;
            if (t + 1 < nkb) stage(kb2 + 128, cur ^ 1);

#pragma unroll
            for (int p = 0; p < 2; ++p) {
                const int kbp = kb2 + p * 64;
                if (kbp < q0 + 64) {       // wave-uniform: skip fully-masked
                    const bool diag = (kbp + 63 > q0);

                    // K fragments from LDS (swizzled read), rows p*64..+63
                    bf16x8 kf[4][2];
#pragma unroll
                    for (int nt = 0; nt < 4; ++nt) {
                        const int row = p * 64 + nt * 16 + l16;
#pragma unroll
                        for (int hf = 0; hf < 2; ++hf)
                            kf[nt][hf] = *(const bf16x8*)
                                &lK[cur][row * 64 +
                                         (((hf * 4 + quad) ^ (row & 7)) * 8)];
                    }

                    // scores (transposed) + exp + in-lane bf16 pack
                    unsigned pk[4][4][2];
#pragma unroll
                    for (int nt = 0; nt < 4; ++nt) {
                        const int krow = kbp + nt * 16 + quad * 4;
#pragma unroll
                        for (int qs = 0; qs < 4; ++qs) {
                            f32x4 s = (f32x4){0.f, 0.f, 0.f, 0.f};
                            s = __builtin_amdgcn_mfma_f32_16x16x32_bf16(
                                kf[nt][0], qf[qs][0], s, 0, 0, 0);
                            s = __builtin_amdgcn_mfma_f32_16x16x32_bf16(
                                kf[nt][1], qf[qs][1], s, 0, 0, 0);
                            if (diag) {    // exec-skipped off the diagonal
                                const int qcol = q0 + qs * 16 + l16;
#pragma unroll
                                for (int r = 0; r < 4; ++r)
                                    if (krow + r > qcol) s[r] = -1e30f;
                            }
                            float ev[4];
#pragma unroll
                            for (int r = 0; r < 4; ++r) {
                                float e = exp2_raw(s[r]);  // scaled via Q-fold
                                ps[qs] += e;
                                ev[r] = e;
                            }
                            pk[nt][qs][0] = cvtpk_bf16(ev[0], ev[1]);
                            pk[nt][qs][1] = cvtpk_bf16(ev[2], ev[3]);
                        }
                    }

                    // register-only P-transpose + PV accumulation
#pragma unroll
                    for (int kk = 0; kk < 2; ++kk) {
                        // V fragments for this k-half from sub-tile p
                        bf16x8 vfk[4];
#pragma unroll
                        for (int nt = 0; nt < 4; ++nt) {
                            const int row = nt * 16 + l16;
                            vfk[nt] = *(const bf16x8*)
                                &lV[cur][p][row * 64 +
                                            (((kk * 4 + quad) ^ (row & 7)) * 8)];
                        }
#pragma unroll
                        for (int qs = 0; qs < 4; ++qs) {
                            u32x2 sA = __builtin_amdgcn_permlane32_swap(
                                pk[2 * kk][qs][0], pk[2 * kk + 1][qs][0],
                                false, false);
                            u32x2 sB = __builtin_amdgcn_permlane32_swap(
                                pk[2 * kk][qs][1], pk[2 * kk + 1][qs][1],
                                false, false);
                            u32x2 tA = __builtin_amdgcn_permlane16_swap(
                                sA.x, sA.y, false, false);
                            u32x2 tB = __builtin_amdgcn_permlane16_swap(
                                sB.x, sB.y, false, false);
                            union { unsigned d[4]; bf16x8 v; } pf;
                            pf.d[0] = tA.x;  // k-pair (0,1) of quad*8
                            pf.d[1] = tB.x;  // k-pair (2,3)
                            pf.d[2] = tA.y;  // k-pair (4,5)
                            pf.d[3] = tB.y;  // k-pair (6,7)
#pragma unroll
                            for (int nt = 0; nt < 4; ++nt)
                                o[qs][nt] =
                                    __builtin_amdgcn_mfma_f32_16x16x32_bf16(
                                        pf.v, vfk[nt], o[qs][nt], 0, 0, 0);
                        }
                    }
                }
            }
            __syncthreads();   // next tile staged + this tile's reads done
        }

        // epilogue: quad-reduce row sums, redistribute, O/l, write bf16
#pragma unroll
        for (int qs = 0; qs < 4; ++qs) {
            float tsum = ps[qs];
            tsum += __shfl_xor(tsum, 16);
            tsum += __shfl_xor(tsum, 32);
            // every lane now holds rowsum(q = q0+qs*16+l16)
            float inv[4];
#pragma unroll
            for (int r = 0; r < 4; ++r)
                inv[r] = 1.0f / __shfl(tsum, quad * 4 + r);
#pragma unroll
            for (int nt = 0; nt < 4; ++nt) {
                int d = nt * 16 + l16;
#pragma unroll
                for (int r = 0; r < 4; ++r) {
                    int s = q0 + qs * 16 + quad * 4 + r;
                    Ou[(size_t)(b * SS + s) * DD + h * HDD + d] =
                        f2bf(o[qs][nt][r] * inv[r]);
                }
            }
        }
        // no barrier needed between phases: epilogue touches no LDS, and all
        // LDS reads of the last tile completed before its __syncthreads.
    }
}

// ---------------------------------------------------------------------------
// Buffer plan.  TSZ = B*S*D bf16 = 16 MiB; WSZ = D*D bf16 = 2 MiB.
//   d_out (32 MiB fp32): [0,TSZ) = xb, [TSZ,2*TSZ) = Vt — both dead before
//     the final GEMM overwrites d_out (it reads only Ob, wb3).
//   ws: Qb | Kb | Ob | wb0..3 = 56 MiB.  wb0..wb2 contiguous = stacked QKV W.
// ---------------------------------------------------------------------------
extern "C" void kernel_launch(void* const* d_in, const int* in_sizes, int n_in,
                              void* d_out, int out_size, void* d_ws,
                              size_t ws_size, hipStream_t stream)
{
    const float* x    = (const float*)d_in[0];
    const float* fcos = (const float*)d_in[1];
    const float* fsin = (const float*)d_in[2];
    const float* wq   = (const float*)d_in[3];
    const float* wk   = (const float*)d_in[4];
    const float* wv   = (const float*)d_in[5];
    const float* wo   = (const float*)d_in[6];

    char* ws = (char*)d_ws;
    const size_t TSZ = (size_t)BB * SS * DD * sizeof(bf16_t);  // 16 MiB
    const size_t WSZ = (size_t)DD * DD * sizeof(bf16_t);       // 2 MiB
    bf16_t* Qb  = (bf16_t*)(ws);
    bf16_t* Kb  = (bf16_t*)(ws + TSZ);
    bf16_t* Ob  = (bf16_t*)(ws + 2 * TSZ);
    bf16_t* wb0 = (bf16_t*)(ws + 3 * TSZ);
    bf16_t* wb1 = (bf16_t*)(ws + 3 * TSZ + WSZ);
    bf16_t* wb2 = (bf16_t*)(ws + 3 * TSZ + 2 * WSZ);
    bf16_t* wb3 = (bf16_t*)(ws + 3 * TSZ + 3 * WSZ);
    bf16_t* xb  = (bf16_t*)d_out;
    bf16_t* Vt  = (bf16_t*)((char*)d_out + TSZ);

    dim3 bb(256);
    cvt1<<<dim3(4096), bb, 0, stream>>>(x, xb);
    cvt4<<<dim3(512, 4), bb, 0, stream>>>(wq, wk, wv, wo, wb0, wb1, wb2, wb3);

    const float sscale = 0.125f * 1.44269504088896f;  // 1/sqrt(64)*log2(e)
    gemm_qkv<<<dim3(24, 64), bb, 0, stream>>>(xb, wb0, Qb, Kb, Vt,
                                              fcos, fsin, sscale);
    attn<<<dim3(256), bb, 0, stream>>>(Qb, Kb, Vt, Ob);
    gemm_out<<<dim3(8, 64), bb, 0, stream>>>(Ob, wb3, (float*)d_out);
}

// Round 9
// 250.971 us; speedup vs baseline: 1.1160x; 1.1079x over previous
//
#include <hip/hip_runtime.h>
#include <hip/hip_bf16.h>
#include <cstdint>
#include <cstddef>

// Problem constants
#define BB 4
#define SS 2048
#define DD 1024
#define HH 16
#define HDD 64

typedef __bf16 bf16_t;
typedef __bf16 bf16x8 __attribute__((ext_vector_type(8)));
typedef float f32x4 __attribute__((ext_vector_type(4)));
typedef unsigned u32x2 __attribute__((ext_vector_type(2)));

__device__ __forceinline__ unsigned short f2bf(float f) {
    unsigned u = __float_as_uint(f);
    unsigned r = (u + 0x7FFFu + ((u >> 16) & 1u)) >> 16;
    return (unsigned short)r;
}
__device__ __forceinline__ bf16_t f2bf16(float f) {
    return __builtin_bit_cast(bf16_t, f2bf(f));
}
__device__ __forceinline__ bf16x8 cvt8(float4 a, float4 b) {
    bf16x8 r;
    r[0] = f2bf16(a.x); r[1] = f2bf16(a.y);
    r[2] = f2bf16(a.z); r[3] = f2bf16(a.w);
    r[4] = f2bf16(b.x); r[5] = f2bf16(b.y);
    r[6] = f2bf16(b.z); r[7] = f2bf16(b.w);
    return r;
}
// packed f32x2 -> bf16x2 (RNE), lo16 = bf16(lo), hi16 = bf16(hi)
__device__ __forceinline__ unsigned cvtpk_bf16(float lo, float hi) {
    unsigned r;
    asm("v_cvt_pk_bf16_f32 %0, %1, %2" : "=v"(r) : "v"(lo), "v"(hi));
    return r;
}
// raw HW exp2: skips libm's denorm-guard sequence. 2^(-1e30) -> 0 in HW.
__device__ __forceinline__ float exp2_raw(float x) {
    float r;
    asm("v_exp_f32 %0, %1" : "=v"(r) : "v"(x));
    return r;
}

// async global->LDS, 16B per lane; LDS dest = wave-uniform base + lane*16
#define GLL16(gp, lp)                                                          \
    __builtin_amdgcn_global_load_lds(                                          \
        (const __attribute__((address_space(1))) void*)(gp),                   \
        (__attribute__((address_space(3))) void*)(lp), 16, 0, 0)

// ---------------------------------------------------------------------------
// fp32 -> bf16 converters (memory-bound, one-shot)
// ---------------------------------------------------------------------------
__global__ __launch_bounds__(256) void cvt1(const float* __restrict__ in,
                                            bf16_t* __restrict__ out) {
    size_t i = (size_t)blockIdx.x * 256 + threadIdx.x;
    const float4* p = (const float4*)in + i * 2;
    *(bf16x8*)(out + i * 8) = cvt8(p[0], p[1]);
}
__global__ __launch_bounds__(256) void cvt4(
    const float* __restrict__ w0, const float* __restrict__ w1,
    const float* __restrict__ w2, const float* __restrict__ w3,
    bf16_t* __restrict__ o0, bf16_t* __restrict__ o1,
    bf16_t* __restrict__ o2, bf16_t* __restrict__ o3) {
    const float* in = blockIdx.y == 0 ? w0 : blockIdx.y == 1 ? w1
                    : blockIdx.y == 2 ? w2 : w3;
    bf16_t* out = blockIdx.y == 0 ? o0 : blockIdx.y == 1 ? o1
                : blockIdx.y == 2 ? o2 : o3;
    size_t i = (size_t)blockIdx.x * 256 + threadIdx.x;
    const float4* p = (const float4*)in + i * 2;
    *(bf16x8*)(out + i * 8) = cvt8(p[0], p[1]);
}

// ---------------------------------------------------------------------------
// Fused QKV projection: C(8192x3072) = xb(8192x1024) @ [wq;wk;wv]^T.
// ---------------------------------------------------------------------------
__global__ __launch_bounds__(256, 2) void gemm_qkv(
    const bf16_t* __restrict__ A, const bf16_t* __restrict__ Wall,
    bf16_t* __restrict__ Qb, bf16_t* __restrict__ Kb,
    bf16_t* __restrict__ Vt,
    const float* __restrict__ fcos, const float* __restrict__ fsin,
    float qscale)
{
    constexpr int K = 1024;
    __shared__ alignas(16) bf16_t lA[128 * 64];
    __shared__ alignas(16) bf16_t lB[128 * 64];

    const int tid  = threadIdx.x;
    const int w    = tid >> 6;
    const int lane = tid & 63;
    const int quad = lane >> 4;
    const int l16  = lane & 15;
    const int wm   = w >> 1;
    const int wn   = w & 1;
    const int m0   = blockIdx.y * 128;
    const int n0   = blockIdx.x * 128;   // 0..2944 over the stacked weights
    const int sub  = n0 >> 10;           // 0=Q, 1=K, 2=V (block-uniform)

    f32x4 acc[4][4];
#pragma unroll
    for (int i = 0; i < 4; i++)
#pragma unroll
        for (int j = 0; j < 4; j++) acc[i][j] = (f32x4){0.f, 0.f, 0.f, 0.f};

    const int srow8 = lane >> 3;
    const int slot  = lane & 7;

    for (int k0 = 0; k0 < K; k0 += 64) {
#pragma unroll
        for (int i = 0; i < 4; ++i) {
            int row = w * 32 + i * 8;
            GLL16(A + (size_t)(m0 + row + srow8) * K + k0 + slot * 8,
                  &lA[row * 64]);
            GLL16(Wall + (size_t)(n0 + row + srow8) * K + k0 + slot * 8,
                  &lB[row * 64]);
        }
        __syncthreads();
#pragma unroll
        for (int kk = 0; kk < 2; ++kk) {
            bf16x8 af[4], bfr[4];
#pragma unroll
            for (int mt = 0; mt < 4; ++mt)
                af[mt] = *(const bf16x8*)
                    &lA[(wm * 64 + mt * 16 + l16) * 64 + (kk * 4 + quad) * 8];
#pragma unroll
            for (int nt = 0; nt < 4; ++nt)
                bfr[nt] = *(const bf16x8*)
                    &lB[(wn * 64 + nt * 16 + l16) * 64 + (kk * 4 + quad) * 8];
#pragma unroll
            for (int mt = 0; mt < 4; ++mt)
#pragma unroll
                for (int nt = 0; nt < 4; ++nt)
                    acc[mt][nt] = __builtin_amdgcn_mfma_f32_16x16x32_bf16(
                        af[mt], bfr[nt], acc[mt][nt], 0, 0, 0);
        }
        __syncthreads();
    }

    if (sub < 2) {
        // RoPE + scale, write bf16 (B,H,S,HD)
        unsigned short* Cu = (unsigned short*)(sub == 0 ? Qb : Kb);
        const float scale = sub == 0 ? qscale : 1.0f;
#pragma unroll
        for (int mt = 0; mt < 4; ++mt) {
#pragma unroll
            for (int nt = 0; nt < 4; ++nt) {
                int col  = (n0 & 1023) + wn * 64 + nt * 16 + l16;
                int h    = col >> 6;
                int d    = col & 63;
                int pidx = d >> 1;
                bool even = (col & 1) == 0;
#pragma unroll
                for (int r = 0; r < 4; ++r) {
                    int m = m0 + wm * 64 + mt * 16 + quad * 4 + r;
                    int b = m >> 11;   // / S
                    int s = m & 2047;  // % S
                    float v  = acc[mt][nt][r];
                    float p  = __shfl_xor(v, 1);
                    float c  = fcos[s * 32 + pidx];
                    float sn = fsin[s * 32 + pidx];
                    float o  = even ? (v * c - p * sn) : (p * sn + v * c);
                    Cu[(size_t)((b * HH + h) * SS + s) * HDD + d] =
                        f2bf(o * scale);
                }
            }
        }
    } else {
        // V: write bf16 transposed (B,H,HD,S)
        unsigned short* Cu = (unsigned short*)Vt;
#pragma unroll
        for (int mt = 0; mt < 4; ++mt) {
#pragma unroll
            for (int nt = 0; nt < 4; ++nt) {
                int col = (n0 & 1023) + wn * 64 + nt * 16 + l16;
                int h = col >> 6, d = col & 63;
#pragma unroll
                for (int r = 0; r < 4; ++r) {
                    int m = m0 + wm * 64 + mt * 16 + quad * 4 + r;
                    int b = m >> 11, s = m & 2047;
                    Cu[(size_t)((b * HH + h) * HDD + d) * SS + s] =
                        f2bf(acc[mt][nt][r]);
                }
            }
        }
    }
}

// ---------------------------------------------------------------------------
// Final projection: C(MxN) = A(MxK) @ W^T, fp32 row-major output.
// ---------------------------------------------------------------------------
__global__ __launch_bounds__(256, 2) void gemm_out(
    const bf16_t* __restrict__ A, const bf16_t* __restrict__ W,
    float* __restrict__ Cf)
{
    constexpr int K = 1024, N = 1024;
    __shared__ alignas(16) bf16_t lA[128 * 64];
    __shared__ alignas(16) bf16_t lB[128 * 64];

    const int tid  = threadIdx.x;
    const int w    = tid >> 6;
    const int lane = tid & 63;
    const int quad = lane >> 4;
    const int l16  = lane & 15;
    const int wm   = w >> 1;
    const int wn   = w & 1;
    const int m0   = blockIdx.y * 128;
    const int n0   = blockIdx.x * 128;

    f32x4 acc[4][4];
#pragma unroll
    for (int i = 0; i < 4; i++)
#pragma unroll
        for (int j = 0; j < 4; j++) acc[i][j] = (f32x4){0.f, 0.f, 0.f, 0.f};

    const int srow8 = lane >> 3;
    const int slot  = lane & 7;

    for (int k0 = 0; k0 < K; k0 += 64) {
#pragma unroll
        for (int i = 0; i < 4; ++i) {
            int row = w * 32 + i * 8;
            GLL16(A + (size_t)(m0 + row + srow8) * K + k0 + slot * 8,
                  &lA[row * 64]);
            GLL16(W + (size_t)(n0 + row + srow8) * K + k0 + slot * 8,
                  &lB[row * 64]);
        }
        __syncthreads();
#pragma unroll
        for (int kk = 0; kk < 2; ++kk) {
            bf16x8 af[4], bfr[4];
#pragma unroll
            for (int mt = 0; mt < 4; ++mt)
                af[mt] = *(const bf16x8*)
                    &lA[(wm * 64 + mt * 16 + l16) * 64 + (kk * 4 + quad) * 8];
#pragma unroll
            for (int nt = 0; nt < 4; ++nt)
                bfr[nt] = *(const bf16x8*)
                    &lB[(wn * 64 + nt * 16 + l16) * 64 + (kk * 4 + quad) * 8];
#pragma unroll
            for (int mt = 0; mt < 4; ++mt)
#pragma unroll
                for (int nt = 0; nt < 4; ++nt)
                    acc[mt][nt] = __builtin_amdgcn_mfma_f32_16x16x32_bf16(
                        af[mt], bfr[nt], acc[mt][nt], 0, 0, 0);
        }
        __syncthreads();
    }

#pragma unroll
    for (int mt = 0; mt < 4; ++mt) {
        int mrow = m0 + wm * 64 + mt * 16 + quad * 4;
#pragma unroll
        for (int nt = 0; nt < 4; ++nt) {
            int col = n0 + wn * 64 + nt * 16 + l16;
#pragma unroll
            for (int r = 0; r < 4; ++r)
                Cf[(size_t)(mrow + r) * N + col] = acc[mt][nt][r];
        }
    }
}

// ---------------------------------------------------------------------------
// Flash attention v12 — the three-way combination no prior round had at once:
//   (1) lean VALU body (raw exp2, diag-hoist, in-reg softmax)   [R5]
//   (2) stable 2 blocks/CU for the WHOLE dispatch               [R3]
//   (3) zero-tail uniform load: paired (T, 15-T) 128-row tiles  [R8 idea]
// Series reconciliation: MFMA-busy is constant (~work); R5 cut VALU 40% but
// broke residency (tail); R8 balanced perfectly but at 1 wave/SIMD all
// dependency latencies were exposed (stalls ~60% of cycles). Regime: VALU +
// exposed-latency bound -> need diet AND >=2 waves/SIMD AND no tail.
// Geometry: block = 128 q-rows (4 waves x 32), KVBLK=128 (two 64-passes,
// fat tiles halve barrier count), pairing (T,15-T) -> every block exactly
// 17 tiles; grid 512 = 2 blocks/CU co-resident (32KB LDS, single-buffered:
// the co-resident block hides staging drains, proven in R3).
// ---------------------------------------------------------------------------
__global__ __launch_bounds__(256, 2) void attn(
    const bf16_t* __restrict__ Q, const bf16_t* __restrict__ Kt,
    const bf16_t* __restrict__ Vt, bf16_t* __restrict__ O)
{
    __shared__ alignas(16) bf16_t lK[128 * 64];    // 16 KiB, k-row x hd
    __shared__ alignas(16) bf16_t lV[2][64 * 64];  // 2 x 8 KiB, hd x k-col

    const int tid  = threadIdx.x;
    const int w    = tid >> 6;
    const int lane = tid & 63;
    const int quad = lane >> 4;
    const int l16  = lane & 15;

    // XCD-affinity decode: all 8 blocks of a given bh land on XCD bh&7.
    const int blk  = blockIdx.x;          // 0..511
    const int xcd  = blk & 7;
    const int rest = blk >> 3;            // 0..63
    const int g    = rest & 7;            // pair index 0..7
    const int bh   = ((rest >> 3) << 3) | xcd;

    const int b = bh >> 4, h = bh & 15;
    unsigned short* Ou = (unsigned short*)O;
    const bf16_t* Qb = Q  + (size_t)bh * SS * HDD;
    const bf16_t* Kb = Kt + (size_t)bh * SS * HDD;
    const bf16_t* Vb = Vt + (size_t)bh * HDD * SS;

    // staging lane geometry: 8-row x 8-chunk GLL16 groups, source chunk
    // XOR-swizzled by (row&7) (involution; read side applies the same XOR).
    const int row8 = lane >> 3;            // 0..7 row within a group
    const int chk  = lane & 7;             // 16B chunk within a 128B row

    for (int phase = 0; phase < 2; ++phase) {
        const int Tp  = phase ? 15 - g : g;   // 128-row super-tile index
        const int q0  = Tp * 128 + w * 32;    // this wave's 32 q-rows
        const int nkb = Tp + 1;               // 128-wide k-tile count
        // per block: (g+1) + (16-g) = 17 tiles, uniform across all blocks.

        // Q fragments (B-operand of swapped QK^T), direct global
        bf16x8 qf[2][2];
#pragma unroll
        for (int qs = 0; qs < 2; ++qs) {
            const bf16_t* qp =
                Qb + (size_t)(q0 + qs * 16 + l16) * HDD + quad * 8;
            qf[qs][0] = *(const bf16x8*)(qp);
            qf[qs][1] = *(const bf16x8*)(qp + 32);
        }

        f32x4 o[2][4];
        float ps[2];
#pragma unroll
        for (int qs = 0; qs < 2; ++qs) {
            ps[qs] = 0.f;
#pragma unroll
            for (int i = 0; i < 4; ++i) o[qs][i] = (f32x4){0.f, 0.f, 0.f, 0.f};
        }

        for (int t = 0; t < nkb; ++t) {
            const int kb2 = t * 128;

            // cooperative stage: K rows kb2..kb2+127 (4 GLL16/wave),
            // V d-rows 0..63 as two 64-col sub-tiles (4 GLL16/wave)
#pragma unroll
            for (int i = 0; i < 4; ++i) {
                int rbase = w * 32 + i * 8;
                int row   = rbase + row8;
                GLL16(Kb + (size_t)(kb2 + row) * HDD + ((chk ^ (row & 7)) * 8),
                      &lK[rbase * 64]);
            }
#pragma unroll
            for (int pp = 0; pp < 2; ++pp)
#pragma unroll
                for (int i = 0; i < 2; ++i) {
                    int rbase = w * 16 + i * 8;
                    int row   = rbase + row8;
                    GLL16(Vb + (size_t)row * SS + kb2 + pp * 64 +
                              ((chk ^ (row & 7)) * 8),
                          &lV[pp][rbase * 64]);
                }
            __syncthreads();   // tiles ready (co-resident block hides drain)

#pragma unroll
            for (int p = 0; p < 2; ++p) {
                const int kbp = kb2 + p * 64;
                if (kbp < q0 + 32) {       // wave-uniform: skip fully-masked
                    const bool diag = (kbp + 63 > q0);

                    // K fragments from LDS (swizzled read), rows p*64..+63
                    bf16x8 kf[4][2];
#pragma unroll
                    for (int nt = 0; nt < 4; ++nt) {
                        const int row = p * 64 + nt * 16 + l16;
#pragma unroll
                        for (int hf = 0; hf < 2; ++hf)
                            kf[nt][hf] = *(const bf16x8*)
                                &lK[row * 64 +
                                    (((hf * 4 + quad) ^ (row & 7)) * 8)];
                    }

                    // scores (transposed) + exp + in-lane bf16 pack
                    unsigned pk[4][2][2];
#pragma unroll
                    for (int nt = 0; nt < 4; ++nt) {
                        const int krow = kbp + nt * 16 + quad * 4;
#pragma unroll
                        for (int qs = 0; qs < 2; ++qs) {
                            f32x4 s = (f32x4){0.f, 0.f, 0.f, 0.f};
                            s = __builtin_amdgcn_mfma_f32_16x16x32_bf16(
                                kf[nt][0], qf[qs][0], s, 0, 0, 0);
                            s = __builtin_amdgcn_mfma_f32_16x16x32_bf16(
                                kf[nt][1], qf[qs][1], s, 0, 0, 0);
                            if (diag) {    // exec-skipped off the diagonal
                                const int qcol = q0 + qs * 16 + l16;
#pragma unroll
                                for (int r = 0; r < 4; ++r)
                                    if (krow + r > qcol) s[r] = -1e30f;
                            }
                            float ev[4];
#pragma unroll
                            for (int r = 0; r < 4; ++r) {
                                float e = exp2_raw(s[r]);  // scaled via Q-fold
                                ps[qs] += e;
                                ev[r] = e;
                            }
                            pk[nt][qs][0] = cvtpk_bf16(ev[0], ev[1]);
                            pk[nt][qs][1] = cvtpk_bf16(ev[2], ev[3]);
                        }
                    }

                    // register-only P-transpose + PV accumulation
#pragma unroll
                    for (int kk = 0; kk < 2; ++kk) {
                        bf16x8 vfk[4];
#pragma unroll
                        for (int nt = 0; nt < 4; ++nt) {
                            const int row = nt * 16 + l16;
                            vfk[nt] = *(const bf16x8*)
                                &lV[p][row * 64 +
                                       (((kk * 4 + quad) ^ (row & 7)) * 8)];
                        }
#pragma unroll
                        for (int qs = 0; qs < 2; ++qs) {
                            u32x2 sA = __builtin_amdgcn_permlane32_swap(
                                pk[2 * kk][qs][0], pk[2 * kk + 1][qs][0],
                                false, false);
                            u32x2 sB = __builtin_amdgcn_permlane32_swap(
                                pk[2 * kk][qs][1], pk[2 * kk + 1][qs][1],
                                false, false);
                            u32x2 tA = __builtin_amdgcn_permlane16_swap(
                                sA.x, sA.y, false, false);
                            u32x2 tB = __builtin_amdgcn_permlane16_swap(
                                sB.x, sB.y, false, false);
                            union { unsigned d[4]; bf16x8 v; } pf;
                            pf.d[0] = tA.x;  // k-pair (0,1) of quad*8
                            pf.d[1] = tB.x;  // k-pair (2,3)
                            pf.d[2] = tA.y;  // k-pair (4,5)
                            pf.d[3] = tB.y;  // k-pair (6,7)
#pragma unroll
                            for (int nt = 0; nt < 4; ++nt)
                                o[qs][nt] =
                                    __builtin_amdgcn_mfma_f32_16x16x32_bf16(
                                        pf.v, vfk[nt], o[qs][nt], 0, 0, 0);
                        }
                    }
                }
            }
            __syncthreads();   // all reads done before next stage overwrites
        }

        // epilogue: quad-reduce row sums, redistribute, O/l, write bf16
#pragma unroll
        for (int qs = 0; qs < 2; ++qs) {
            float tsum = ps[qs];
            tsum += __shfl_xor(tsum, 16);
            tsum += __shfl_xor(tsum, 32);
            float inv[4];
#pragma unroll
            for (int r = 0; r < 4; ++r)
                inv[r] = 1.0f / __shfl(tsum, quad * 4 + r);
#pragma unroll
            for (int nt = 0; nt < 4; ++nt) {
                int d = nt * 16 + l16;
#pragma unroll
                for (int r = 0; r < 4; ++r) {
                    int s = q0 + qs * 16 + quad * 4 + r;
                    Ou[(size_t)(b * SS + s) * DD + h * HDD + d] =
                        f2bf(o[qs][nt][r] * inv[r]);
                }
            }
        }
        // phase boundary: last tile's trailing __syncthreads ordered all
        // LDS reads before the next phase's staging overwrites.
    }
}

// ---------------------------------------------------------------------------
// Buffer plan.  TSZ = B*S*D bf16 = 16 MiB; WSZ = D*D bf16 = 2 MiB.
//   d_out (32 MiB fp32): [0,TSZ) = xb, [TSZ,2*TSZ) = Vt — both dead before
//     the final GEMM overwrites d_out (it reads only Ob, wb3).
//   ws: Qb | Kb | Ob | wb0..3 = 56 MiB.  wb0..wb2 contiguous = stacked QKV W.
// ---------------------------------------------------------------------------
extern "C" void kernel_launch(void* const* d_in, const int* in_sizes, int n_in,
                              void* d_out, int out_size, void* d_ws,
                              size_t ws_size, hipStream_t stream)
{
    const float* x    = (const float*)d_in[0];
    const float* fcos = (const float*)d_in[1];
    const float* fsin = (const float*)d_in[2];
    const float* wq   = (const float*)d_in[3];
    const float* wk   = (const float*)d_in[4];
    const float* wv   = (const float*)d_in[5];
    const float* wo   = (const float*)d_in[6];

    char* ws = (char*)d_ws;
    const size_t TSZ = (size_t)BB * SS * DD * sizeof(bf16_t);  // 16 MiB
    const size_t WSZ = (size_t)DD * DD * sizeof(bf16_t);       // 2 MiB
    bf16_t* Qb  = (bf16_t*)(ws);
    bf16_t* Kb  = (bf16_t*)(ws + TSZ);
    bf16_t* Ob  = (bf16_t*)(ws + 2 * TSZ);
    bf16_t* wb0 = (bf16_t*)(ws + 3 * TSZ);
    bf16_t* wb1 = (bf16_t*)(ws + 3 * TSZ + WSZ);
    bf16_t* wb2 = (bf16_t*)(ws + 3 * TSZ + 2 * WSZ);
    bf16_t* wb3 = (bf16_t*)(ws + 3 * TSZ + 3 * WSZ);
    bf16_t* xb  = (bf16_t*)d_out;
    bf16_t* Vt  = (bf16_t*)((char*)d_out + TSZ);

    dim3 bb(256);
    cvt1<<<dim3(4096), bb, 0, stream>>>(x, xb);
    cvt4<<<dim3(512, 4), bb, 0, stream>>>(wq, wk, wv, wo, wb0, wb1, wb2, wb3);

    const float sscale = 0.125f * 1.44269504088896f;  // 1/sqrt(64)*log2(e)
    gemm_qkv<<<dim3(24, 64), bb, 0, stream>>>(xb, wb0, Qb, Kb, Vt,
                                              fcos, fsin, sscale);
    attn<<<dim3(512), bb, 0, stream>>>(Qb, Kb, Vt, Ob);
    gemm_out<<<dim3(8, 64), bb, 0, stream>>>(Ob, wb3, (float*)d_out);
}

// Round 10
// 229.554 us; speedup vs baseline: 1.2201x; 1.0933x over previous
//
#include <hip/hip_runtime.h>
#include <hip/hip_bf16.h>
#include <cstdint>
#include <cstddef>

// Problem constants
#define BB 4
#define SS 2048
#define DD 1024
#define HH 16
#define HDD 64

typedef __bf16 bf16_t;
typedef __bf16 bf16x8 __attribute__((ext_vector_type(8)));
typedef float f32x4 __attribute__((ext_vector_type(4)));
typedef unsigned u32x2 __attribute__((ext_vector_type(2)));

__device__ __forceinline__ unsigned short f2bf(float f) {
    unsigned u = __float_as_uint(f);
    unsigned r = (u + 0x7FFFu + ((u >> 16) & 1u)) >> 16;
    return (unsigned short)r;
}
__device__ __forceinline__ bf16_t f2bf16(float f) {
    return __builtin_bit_cast(bf16_t, f2bf(f));
}
__device__ __forceinline__ bf16x8 cvt8(float4 a, float4 b) {
    bf16x8 r;
    r[0] = f2bf16(a.x); r[1] = f2bf16(a.y);
    r[2] = f2bf16(a.z); r[3] = f2bf16(a.w);
    r[4] = f2bf16(b.x); r[5] = f2bf16(b.y);
    r[6] = f2bf16(b.z); r[7] = f2bf16(b.w);
    return r;
}
// packed f32x2 -> bf16x2 (RNE), lo16 = bf16(lo), hi16 = bf16(hi)
__device__ __forceinline__ unsigned cvtpk_bf16(float lo, float hi) {
    unsigned r;
    asm("v_cvt_pk_bf16_f32 %0, %1, %2" : "=v"(r) : "v"(lo), "v"(hi));
    return r;
}
// raw HW exp2: skips libm's denorm-guard sequence. 2^(-1e30) -> 0 in HW.
__device__ __forceinline__ float exp2_raw(float x) {
    float r;
    asm("v_exp_f32 %0, %1" : "=v"(r) : "v"(x));
    return r;
}

// async global->LDS, 16B per lane; LDS dest = wave-uniform base + lane*16
#define GLL16(gp, lp)                                                          \
    __builtin_amdgcn_global_load_lds(                                          \
        (const __attribute__((address_space(1))) void*)(gp),                   \
        (__attribute__((address_space(3))) void*)(lp), 16, 0, 0)

// ---------------------------------------------------------------------------
// fp32 -> bf16 converter, merged: blocks [0,4096) convert x (8M elems),
// blocks [4096,6144) convert the four 1M-elem weight matrices (512 each).
// ---------------------------------------------------------------------------
__global__ __launch_bounds__(256) void cvtall(
    const float* __restrict__ x,
    const float* __restrict__ w0, const float* __restrict__ w1,
    const float* __restrict__ w2, const float* __restrict__ w3,
    bf16_t* __restrict__ xb,
    bf16_t* __restrict__ o0, bf16_t* __restrict__ o1,
    bf16_t* __restrict__ o2, bf16_t* __restrict__ o3)
{
    const int bx = blockIdx.x;
    const float* in;
    bf16_t* out;
    size_t i;
    if (bx < 4096) {
        in = x; out = xb;
        i = (size_t)bx * 256 + threadIdx.x;
    } else {
        const int g = bx - 4096;
        const int s = g >> 9;          // 0..3
        in  = s == 0 ? w0 : s == 1 ? w1 : s == 2 ? w2 : w3;
        out = s == 0 ? o0 : s == 1 ? o1 : s == 2 ? o2 : o3;
        i = (size_t)(g & 511) * 256 + threadIdx.x;
    }
    const float4* p = (const float4*)in + i * 2;
    *(bf16x8*)(out + i * 8) = cvt8(p[0], p[1]);
}

// ---------------------------------------------------------------------------
// Fused QKV projection: C(8192x3072) = xb(8192x1024) @ [wq;wk;wv]^T.
// R10: (1) T2 XOR-involution LDS swizzle (the attn staging pattern) on both
// lA/lB — R9 measured 18.9M SQ_LDS_BANK_CONFLICT cycles (38% of per-CU wall
// time) from 16-way ds_read_b128 conflicts at 128B row stride. (2) Bijective
// XCD-chunked block swizzle: each XCD gets 192 consecutive logical tiles
// (8 m-rows x 24 n) -> per-XCD L2 working set 22MB -> 8MB (A panels now
// shared within an XCD; R9 FETCH was 76.8MB vs 22MB of inputs).
// ---------------------------------------------------------------------------
__global__ __launch_bounds__(256, 2) void gemm_qkv(
    const bf16_t* __restrict__ A, const bf16_t* __restrict__ Wall,
    bf16_t* __restrict__ Qb, bf16_t* __restrict__ Kb,
    bf16_t* __restrict__ Vt,
    const float* __restrict__ fcos, const float* __restrict__ fsin,
    float qscale)
{
    constexpr int K = 1024;
    __shared__ alignas(16) bf16_t lA[128 * 64];
    __shared__ alignas(16) bf16_t lB[128 * 64];

    const int tid  = threadIdx.x;
    const int w    = tid >> 6;
    const int lane = tid & 63;
    const int quad = lane >> 4;
    const int l16  = lane & 15;
    const int wm   = w >> 1;
    const int wn   = w & 1;

    // XCD-chunked swizzle (1536 % 8 == 0 -> simple form is bijective):
    // dispatch-linear lid round-robins XCDs; give XCD j the contiguous
    // logical range [j*192, (j+1)*192) = 8 m-rows x 24 n-cols.
    const int lid     = blockIdx.y * 24 + blockIdx.x;
    const int logical = (lid & 7) * 192 + (lid >> 3);
    const int m0      = (logical / 24) * 128;
    const int n0      = (logical % 24) * 128;
    const int sub     = n0 >> 10;        // 0=Q, 1=K, 2=V (block-uniform)

    f32x4 acc[4][4];
#pragma unroll
    for (int i = 0; i < 4; i++)
#pragma unroll
        for (int j = 0; j < 4; j++) acc[i][j] = (f32x4){0.f, 0.f, 0.f, 0.f};

    const int srow8 = lane >> 3;   // row within an 8-row GLL group
    const int slot  = lane & 7;    // 16B chunk within the 128B row

    for (int k0 = 0; k0 < K; k0 += 64) {
#pragma unroll
        for (int i = 0; i < 4; ++i) {
            int rbase = w * 32 + i * 8;
            int row   = rbase + srow8;
            int sc    = (slot ^ (row & 7)) * 8;   // swizzled source chunk
            GLL16(A + (size_t)(m0 + row) * K + k0 + sc, &lA[rbase * 64]);
            GLL16(Wall + (size_t)(n0 + row) * K + k0 + sc, &lB[rbase * 64]);
        }
        __syncthreads();
#pragma unroll
        for (int kk = 0; kk < 2; ++kk) {
            bf16x8 af[4], bfr[4];
#pragma unroll
            for (int mt = 0; mt < 4; ++mt) {
                const int row = wm * 64 + mt * 16 + l16;
                af[mt] = *(const bf16x8*)
                    &lA[row * 64 + (((kk * 4 + quad) ^ (row & 7)) * 8)];
            }
#pragma unroll
            for (int nt = 0; nt < 4; ++nt) {
                const int row = wn * 64 + nt * 16 + l16;
                bfr[nt] = *(const bf16x8*)
                    &lB[row * 64 + (((kk * 4 + quad) ^ (row & 7)) * 8)];
            }
#pragma unroll
            for (int mt = 0; mt < 4; ++mt)
#pragma unroll
                for (int nt = 0; nt < 4; ++nt)
                    acc[mt][nt] = __builtin_amdgcn_mfma_f32_16x16x32_bf16(
                        af[mt], bfr[nt], acc[mt][nt], 0, 0, 0);
        }
        __syncthreads();
    }

    if (sub < 2) {
        // RoPE + scale, write bf16 (B,H,S,HD)
        unsigned short* Cu = (unsigned short*)(sub == 0 ? Qb : Kb);
        const float scale = sub == 0 ? qscale : 1.0f;
#pragma unroll
        for (int mt = 0; mt < 4; ++mt) {
#pragma unroll
            for (int nt = 0; nt < 4; ++nt) {
                int col  = (n0 & 1023) + wn * 64 + nt * 16 + l16;
                int h    = col >> 6;
                int d    = col & 63;
                int pidx = d >> 1;
                bool even = (col & 1) == 0;
#pragma unroll
                for (int r = 0; r < 4; ++r) {
                    int m = m0 + wm * 64 + mt * 16 + quad * 4 + r;
                    int b = m >> 11;   // / S
                    int s = m & 2047;  // % S
                    float v  = acc[mt][nt][r];
                    float p  = __shfl_xor(v, 1);
                    float c  = fcos[s * 32 + pidx];
                    float sn = fsin[s * 32 + pidx];
                    float o  = even ? (v * c - p * sn) : (p * sn + v * c);
                    Cu[(size_t)((b * HH + h) * SS + s) * HDD + d] =
                        f2bf(o * scale);
                }
            }
        }
    } else {
        // V: write bf16 transposed (B,H,HD,S)
        unsigned short* Cu = (unsigned short*)Vt;
#pragma unroll
        for (int mt = 0; mt < 4; ++mt) {
#pragma unroll
            for (int nt = 0; nt < 4; ++nt) {
                int col = (n0 & 1023) + wn * 64 + nt * 16 + l16;
                int h = col >> 6, d = col & 63;
#pragma unroll
                for (int r = 0; r < 4; ++r) {
                    int m = m0 + wm * 64 + mt * 16 + quad * 4 + r;
                    int b = m >> 11, s = m & 2047;
                    Cu[(size_t)((b * HH + h) * HDD + d) * SS + s] =
                        f2bf(acc[mt][nt][r]);
                }
            }
        }
    }
}

// ---------------------------------------------------------------------------
// Final projection: C(MxN) = A(MxK) @ W^T, fp32 row-major output.
// R10: same T2 LDS swizzle; XCD chunk = 64 logical tiles (8 m-rows x 8 n)
// -> per-XCD working set A 2MB + W 2MB = 4MB = exactly L2-resident.
// ---------------------------------------------------------------------------
__global__ __launch_bounds__(256, 2) void gemm_out(
    const bf16_t* __restrict__ A, const bf16_t* __restrict__ W,
    float* __restrict__ Cf)
{
    constexpr int K = 1024, N = 1024;
    __shared__ alignas(16) bf16_t lA[128 * 64];
    __shared__ alignas(16) bf16_t lB[128 * 64];

    const int tid  = threadIdx.x;
    const int w    = tid >> 6;
    const int lane = tid & 63;
    const int quad = lane >> 4;
    const int l16  = lane & 15;
    const int wm   = w >> 1;
    const int wn   = w & 1;

    const int lid     = blockIdx.y * 8 + blockIdx.x;       // 0..511
    const int logical = (lid & 7) * 64 + (lid >> 3);
    const int m0      = (logical >> 3) * 128;
    const int n0      = (logical & 7) * 128;

    f32x4 acc[4][4];
#pragma unroll
    for (int i = 0; i < 4; i++)
#pragma unroll
        for (int j = 0; j < 4; j++) acc[i][j] = (f32x4){0.f, 0.f, 0.f, 0.f};

    const int srow8 = lane >> 3;
    const int slot  = lane & 7;

    for (int k0 = 0; k0 < K; k0 += 64) {
#pragma unroll
        for (int i = 0; i < 4; ++i) {
            int rbase = w * 32 + i * 8;
            int row   = rbase + srow8;
            int sc    = (slot ^ (row & 7)) * 8;
            GLL16(A + (size_t)(m0 + row) * K + k0 + sc, &lA[rbase * 64]);
            GLL16(W + (size_t)(n0 + row) * K + k0 + sc, &lB[rbase * 64]);
        }
        __syncthreads();
#pragma unroll
        for (int kk = 0; kk < 2; ++kk) {
            bf16x8 af[4], bfr[4];
#pragma unroll
            for (int mt = 0; mt < 4; ++mt) {
                const int row = wm * 64 + mt * 16 + l16;
                af[mt] = *(const bf16x8*)
                    &lA[row * 64 + (((kk * 4 + quad) ^ (row & 7)) * 8)];
            }
#pragma unroll
            for (int nt = 0; nt < 4; ++nt) {
                const int row = wn * 64 + nt * 16 + l16;
                bfr[nt] = *(const bf16x8*)
                    &lB[row * 64 + (((kk * 4 + quad) ^ (row & 7)) * 8)];
            }
#pragma unroll
            for (int mt = 0; mt < 4; ++mt)
#pragma unroll
                for (int nt = 0; nt < 4; ++nt)
                    acc[mt][nt] = __builtin_amdgcn_mfma_f32_16x16x32_bf16(
                        af[mt], bfr[nt], acc[mt][nt], 0, 0, 0);
        }
        __syncthreads();
    }

#pragma unroll
    for (int mt = 0; mt < 4; ++mt) {
        int mrow = m0 + wm * 64 + mt * 16 + quad * 4;
#pragma unroll
        for (int nt = 0; nt < 4; ++nt) {
            int col = n0 + wn * 64 + nt * 16 + l16;
#pragma unroll
            for (int r = 0; r < 4; ++r)
                Cf[(size_t)(mrow + r) * N + col] = acc[mt][nt][r];
        }
    }
}

// ---------------------------------------------------------------------------
// Flash attention v12 (UNCHANGED from R9 — current best: lean VALU body +
// stable 2 blocks/CU + zero-tail paired (T,15-T) 128-row tiles, 17 fat
// KVBLK=128 k-tiles per block, grid 512).
// ---------------------------------------------------------------------------
__global__ __launch_bounds__(256, 2) void attn(
    const bf16_t* __restrict__ Q, const bf16_t* __restrict__ Kt,
    const bf16_t* __restrict__ Vt, bf16_t* __restrict__ O)
{
    __shared__ alignas(16) bf16_t lK[128 * 64];    // 16 KiB, k-row x hd
    __shared__ alignas(16) bf16_t lV[2][64 * 64];  // 2 x 8 KiB, hd x k-col

    const int tid  = threadIdx.x;
    const int w    = tid >> 6;
    const int lane = tid & 63;
    const int quad = lane >> 4;
    const int l16  = lane & 15;

    // XCD-affinity decode: all 8 blocks of a given bh land on XCD bh&7.
    const int blk  = blockIdx.x;          // 0..511
    const int xcd  = blk & 7;
    const int rest = blk >> 3;            // 0..63
    const int g    = rest & 7;            // pair index 0..7
    const int bh   = ((rest >> 3) << 3) | xcd;

    const int b = bh >> 4, h = bh & 15;
    unsigned short* Ou = (unsigned short*)O;
    const bf16_t* Qb = Q  + (size_t)bh * SS * HDD;
    const bf16_t* Kb = Kt + (size_t)bh * SS * HDD;
    const bf16_t* Vb = Vt + (size_t)bh * HDD * SS;

    const int row8 = lane >> 3;            // 0..7 row within a group
    const int chk  = lane & 7;             // 16B chunk within a 128B row

    for (int phase = 0; phase < 2; ++phase) {
        const int Tp  = phase ? 15 - g : g;   // 128-row super-tile index
        const int q0  = Tp * 128 + w * 32;    // this wave's 32 q-rows
        const int nkb = Tp + 1;               // 128-wide k-tile count

        bf16x8 qf[2][2];
#pragma unroll
        for (int qs = 0; qs < 2; ++qs) {
            const bf16_t* qp =
                Qb + (size_t)(q0 + qs * 16 + l16) * HDD + quad * 8;
            qf[qs][0] = *(const bf16x8*)(qp);
            qf[qs][1] = *(const bf16x8*)(qp + 32);
        }

        f32x4 o[2][4];
        float ps[2];
#pragma unroll
        for (int qs = 0; qs < 2; ++qs) {
            ps[qs] = 0.f;
#pragma unroll
            for (int i = 0; i < 4; ++i) o[qs][i] = (f32x4){0.f, 0.f, 0.f, 0.f};
        }

        for (int t = 0; t < nkb; ++t) {
            const int kb2 = t * 128;

#pragma unroll
            for (int i = 0; i < 4; ++i) {
                int rbase = w * 32 + i * 8;
                int row   = rbase + row8;
                GLL16(Kb + (size_t)(kb2 + row) * HDD + ((chk ^ (row & 7)) * 8),
                      &lK[rbase * 64]);
            }
#pragma unroll
            for (int pp = 0; pp < 2; ++pp)
#pragma unroll
                for (int i = 0; i < 2; ++i) {
                    int rbase = w * 16 + i * 8;
                    int row   = rbase + row8;
                    GLL16(Vb + (size_t)row * SS + kb2 + pp * 64 +
                              ((chk ^ (row & 7)) * 8),
                          &lV[pp][rbase * 64]);
                }
            __syncthreads();

#pragma unroll
            for (int p = 0; p < 2; ++p) {
                const int kbp = kb2 + p * 64;
                if (kbp < q0 + 32) {       // wave-uniform: skip fully-masked
                    const bool diag = (kbp + 63 > q0);

                    bf16x8 kf[4][2];
#pragma unroll
                    for (int nt = 0; nt < 4; ++nt) {
                        const int row = p * 64 + nt * 16 + l16;
#pragma unroll
                        for (int hf = 0; hf < 2; ++hf)
                            kf[nt][hf] = *(const bf16x8*)
                                &lK[row * 64 +
                                    (((hf * 4 + quad) ^ (row & 7)) * 8)];
                    }

                    unsigned pk[4][2][2];
#pragma unroll
                    for (int nt = 0; nt < 4; ++nt) {
                        const int krow = kbp + nt * 16 + quad * 4;
#pragma unroll
                        for (int qs = 0; qs < 2; ++qs) {
                            f32x4 s = (f32x4){0.f, 0.f, 0.f, 0.f};
                            s = __builtin_amdgcn_mfma_f32_16x16x32_bf16(
                                kf[nt][0], qf[qs][0], s, 0, 0, 0);
                            s = __builtin_amdgcn_mfma_f32_16x16x32_bf16(
                                kf[nt][1], qf[qs][1], s, 0, 0, 0);
                            if (diag) {    // exec-skipped off the diagonal
                                const int qcol = q0 + qs * 16 + l16;
#pragma unroll
                                for (int r = 0; r < 4; ++r)
                                    if (krow + r > qcol) s[r] = -1e30f;
                            }
                            float ev[4];
#pragma unroll
                            for (int r = 0; r < 4; ++r) {
                                float e = exp2_raw(s[r]);  // scaled via Q-fold
                                ps[qs] += e;
                                ev[r] = e;
                            }
                            pk[nt][qs][0] = cvtpk_bf16(ev[0], ev[1]);
                            pk[nt][qs][1] = cvtpk_bf16(ev[2], ev[3]);
                        }
                    }

#pragma unroll
                    for (int kk = 0; kk < 2; ++kk) {
                        bf16x8 vfk[4];
#pragma unroll
                        for (int nt = 0; nt < 4; ++nt) {
                            const int row = nt * 16 + l16;
                            vfk[nt] = *(const bf16x8*)
                                &lV[p][row * 64 +
                                       (((kk * 4 + quad) ^ (row & 7)) * 8)];
                        }
#pragma unroll
                        for (int qs = 0; qs < 2; ++qs) {
                            u32x2 sA = __builtin_amdgcn_permlane32_swap(
                                pk[2 * kk][qs][0], pk[2 * kk + 1][qs][0],
                                false, false);
                            u32x2 sB = __builtin_amdgcn_permlane32_swap(
                                pk[2 * kk][qs][1], pk[2 * kk + 1][qs][1],
                                false, false);
                            u32x2 tA = __builtin_amdgcn_permlane16_swap(
                                sA.x, sA.y, false, false);
                            u32x2 tB = __builtin_amdgcn_permlane16_swap(
                                sB.x, sB.y, false, false);
                            union { unsigned d[4]; bf16x8 v; } pf;
                            pf.d[0] = tA.x;  // k-pair (0,1) of quad*8
                            pf.d[1] = tB.x;  // k-pair (2,3)
                            pf.d[2] = tA.y;  // k-pair (4,5)
                            pf.d[3] = tB.y;  // k-pair (6,7)
#pragma unroll
                            for (int nt = 0; nt < 4; ++nt)
                                o[qs][nt] =
                                    __builtin_amdgcn_mfma_f32_16x16x32_bf16(
                                        pf.v, vfk[nt], o[qs][nt], 0, 0, 0);
                        }
                    }
                }
            }
            __syncthreads();   // all reads done before next stage overwrites
        }

        // epilogue: quad-reduce row sums, redistribute, O/l, write bf16
#pragma unroll
        for (int qs = 0; qs < 2; ++qs) {
            float tsum = ps[qs];
            tsum += __shfl_xor(tsum, 16);
            tsum += __shfl_xor(tsum, 32);
            float inv[4];
#pragma unroll
            for (int r = 0; r < 4; ++r)
                inv[r] = 1.0f / __shfl(tsum, quad * 4 + r);
#pragma unroll
            for (int nt = 0; nt < 4; ++nt) {
                int d = nt * 16 + l16;
#pragma unroll
                for (int r = 0; r < 4; ++r) {
                    int s = q0 + qs * 16 + quad * 4 + r;
                    Ou[(size_t)(b * SS + s) * DD + h * HDD + d] =
                        f2bf(o[qs][nt][r] * inv[r]);
                }
            }
        }
    }
}

// ---------------------------------------------------------------------------
// Buffer plan.  TSZ = B*S*D bf16 = 16 MiB; WSZ = D*D bf16 = 2 MiB.
//   d_out (32 MiB fp32): [0,TSZ) = xb, [TSZ,2*TSZ) = Vt — both dead before
//     the final GEMM overwrites d_out (it reads only Ob, wb3).
//   ws: Qb | Kb | Ob | wb0..3 = 56 MiB.  wb0..wb2 contiguous = stacked QKV W.
// ---------------------------------------------------------------------------
extern "C" void kernel_launch(void* const* d_in, const int* in_sizes, int n_in,
                              void* d_out, int out_size, void* d_ws,
                              size_t ws_size, hipStream_t stream)
{
    const float* x    = (const float*)d_in[0];
    const float* fcos = (const float*)d_in[1];
    const float* fsin = (const float*)d_in[2];
    const float* wq   = (const float*)d_in[3];
    const float* wk   = (const float*)d_in[4];
    const float* wv   = (const float*)d_in[5];
    const float* wo   = (const float*)d_in[6];

    char* ws = (char*)d_ws;
    const size_t TSZ = (size_t)BB * SS * DD * sizeof(bf16_t);  // 16 MiB
    const size_t WSZ = (size_t)DD * DD * sizeof(bf16_t);       // 2 MiB
    bf16_t* Qb  = (bf16_t*)(ws);
    bf16_t* Kb  = (bf16_t*)(ws + TSZ);
    bf16_t* Ob  = (bf16_t*)(ws + 2 * TSZ);
    bf16_t* wb0 = (bf16_t*)(ws + 3 * TSZ);
    bf16_t* wb1 = (bf16_t*)(ws + 3 * TSZ + WSZ);
    bf16_t* wb2 = (bf16_t*)(ws + 3 * TSZ + 2 * WSZ);
    bf16_t* wb3 = (bf16_t*)(ws + 3 * TSZ + 3 * WSZ);
    bf16_t* xb  = (bf16_t*)d_out;
    bf16_t* Vt  = (bf16_t*)((char*)d_out + TSZ);

    dim3 bb(256);
    cvtall<<<dim3(6144), bb, 0, stream>>>(x, wq, wk, wv, wo,
                                          xb, wb0, wb1, wb2, wb3);

    const float sscale = 0.125f * 1.44269504088896f;  // 1/sqrt(64)*log2(e)
    gemm_qkv<<<dim3(24, 64), bb, 0, stream>>>(xb, wb0, Qb, Kb, Vt,
                                              fcos, fsin, sscale);
    attn<<<dim3(512), bb, 0, stream>>>(Qb, Kb, Vt, Ob);
    gemm_out<<<dim3(8, 64), bb, 0, stream>>>(Ob, wb3, (float*)d_out);
}